// Round 11
// baseline (850.412 us; speedup 1.0000x reference)
//
#include <hip/hip_runtime.h>
#include <math.h>

#define N_ROWS 16384
#define DIM    2048
#define K_CENT 1000
#define KPAD   1024
#define CDIM   2049   // D+1

// ---------------- MFMA-path workspace layout (bytes) ----------------
// Tiled operand layout: [panel(256 rows)][kc(=k/8)][row(0..255)][8 elems]
#define WS_AH   ((size_t)0)            // 64 MB
#define WS_AL   ((size_t)67108864)     // 64 MB
#define WS_BH   ((size_t)134217728)    // 4 MB
#define WS_BL   ((size_t)138412032)    // 4 MB
#define WS_PSA  ((size_t)142606336)    // 4*16384 f
#define WS_PSB  ((size_t)142868480)    // 4*1024 f
#define WS_IR   ((size_t)142884864)    // 16384 f
#define WS_CN2  ((size_t)142950400)    // 1024 f
#define WS_CL   ((size_t)142954496)    // 1024 f
#define WS_PV   ((size_t)142958592)    // 16384*4 f
#define WS_PI   ((size_t)143220736)    // 16384*4 i
#define WS_NEED ((size_t)143482880)

typedef __attribute__((ext_vector_type(8)))  short          bf16x8;
typedef __attribute__((ext_vector_type(16))) float          f32x16;
typedef __attribute__((ext_vector_type(8)))  unsigned short u16x8;

__device__ __forceinline__ unsigned short f2bf(float x){    // RNE fp32->bf16
  unsigned int u = __float_as_uint(x);
  u += 0x7fffu + ((u >> 16) & 1u);
  return (unsigned short)(u >> 16);
}
__device__ __forceinline__ float bf2f(unsigned short h){
  return __uint_as_float(((unsigned int)h) << 16);
}

typedef const __attribute__((address_space(1))) void gv_t;
typedef __attribute__((address_space(3))) void lv_t;
__device__ __forceinline__ void gload16(const void* g, void* l){
  __builtin_amdgcn_global_load_lds((gv_t*)g, (lv_t*)l, 16, 0, 0);
}

// ---------------- prep: split fp32 -> (hi,lo) bf16 in TILED layout ---------
// Block = (panel p, col-section cs of 512). LDS-staged so both the global
// read (row-major) and the tiled write are coalesced. Fuses row-sumsq
// partials (psum[cs][row]).
__global__ __launch_bounds__(256) void prep_split(
    const float* __restrict__ src, int srcStride, int validRows,
    unsigned short* __restrict__ dH, unsigned short* __restrict__ dL,
    float* __restrict__ psum, int rowsTotal)
{
  const int p = blockIdx.x, cs = blockIdx.y, t = threadIdx.x;
  const int rowBase = p * 256;
  __shared__ float buf[256][65];      // +1 pad: write-phase reads conflict-free
  float s = 0.f;
  const size_t dstBase = (size_t)p * 524288;   // elems
  for (int sl = 0; sl < 8; ++sl){
    const int c0 = cs * 512 + sl * 64;
    __syncthreads();
    for (int i = 0; i < 64; ++i){
      const int r = i * 4 + (t >> 6);
      const int gr = rowBase + r;
      buf[r][t & 63] = (gr < validRows)
                       ? src[(size_t)gr * srcStride + c0 + (t & 63)] : 0.f;
    }
    __syncthreads();
    #pragma unroll
    for (int q = 0; q < 8; ++q){      // thread t owns row t; 8 kc chunks
      u16x8 hv, lv;
      #pragma unroll
      for (int e = 0; e < 8; ++e){
        const float x = buf[t][q*8 + e];
        s = fmaf(x, x, s);
        const unsigned short h = f2bf(x);
        hv[e] = h; lv[e] = f2bf(x - bf2f(h));
      }
      const size_t off = dstBase + (size_t)((c0 >> 3) + q) * 2048 + (size_t)t * 8;
      *(u16x8*)(dH + off) = hv;       // consecutive t -> consecutive 16B
      *(u16x8*)(dL + off) = lv;
    }
  }
  psum[(size_t)cs * rowsTotal + rowBase + t] = s;
}

__global__ __launch_bounds__(256) void finalize_rows(const float* __restrict__ ps,
                                                     float* __restrict__ i2r){
  const int r = blockIdx.x * 256 + threadIdx.x;
  const float s = ps[r] + ps[16384 + r] + ps[2*16384 + r] + ps[3*16384 + r];
  i2r[r] = 0.5f * sqrtf(s + 1.0f);    // + appended-ones col
}

__global__ __launch_bounds__(256) void finalize_cents(const float* __restrict__ ps,
    const float* __restrict__ initc, float* __restrict__ cn2, float* __restrict__ cl){
  const int j = blockIdx.x * 256 + threadIdx.x;
  if (j < K_CENT){
    const float b = initc[(size_t)j * CDIM + DIM];
    cn2[j] = ps[j] + ps[1024 + j] + ps[2048 + j] + ps[3072 + j] + b * b;
    cl[j] = b;
  } else { cn2[j] = INFINITY; cl[j] = 0.f; }
}

// ---------------- MFMA GEMM (bf16x3, 32x32x16), 2-phase dbuf pipeline ------
// Block 256x256, 512 thr = 8 waves (2 wr x 4 wc); wave tile 128x64 = 4x2 frags.
// LDS/buffer 64KB: Ah@0 Al@16K Bh@32K Bl@48K, each [kc4][idx256][16B]; dbuf.
// Tiled globals make each stage a contiguous 16KB copy per matrix.
__global__ __launch_bounds__(512) void dist_mfma2(
    const unsigned short* __restrict__ AhT, const unsigned short* __restrict__ AlT,
    const unsigned short* __restrict__ BhT, const unsigned short* __restrict__ BlT,
    const float* __restrict__ i2r, const float* __restrict__ cn2,
    const float* __restrict__ cl, float* __restrict__ pval, int* __restrict__ pidx)
{
  __shared__ char smem[131072];
  const int t  = threadIdx.x;
  const int l  = t & 63;
  const int wr = (t >> 6) >> 2, wc = (t >> 6) & 3;
  const int lr = l & 31, lh = l >> 5;

  f32x16 acc[4][2];
  #pragma unroll
  for (int m = 0; m < 4; ++m)
    #pragma unroll
    for (int n = 0; n < 2; ++n)
      #pragma unroll
      for (int q = 0; q < 16; ++q) acc[m][n][q] = 0.f;

  const char* pAh = (const char*)AhT + (size_t)blockIdx.x * 1048576;
  const char* pAl = (const char*)AlT + (size_t)blockIdx.x * 1048576;
  const char* pBh = (const char*)BhT + (size_t)blockIdx.y * 1048576;
  const char* pBl = (const char*)BlT + (size_t)blockIdx.y * 1048576;

  auto STAGE = [&](int b, int k0){
    const size_t ko = (size_t)k0 * 512;        // bytes: k0*256 elems * 2B
    char* d = smem + b * 65536;
    gload16(pAh + ko + t*16,         d + t*16);
    gload16(pAh + ko + (t+512)*16,   d + (t+512)*16);
    gload16(pAl + ko + t*16,         d + 16384 + t*16);
    gload16(pAl + ko + (t+512)*16,   d + 16384 + (t+512)*16);
    gload16(pBh + ko + t*16,         d + 32768 + t*16);
    gload16(pBh + ko + (t+512)*16,   d + 32768 + (t+512)*16);
    gload16(pBl + ko + t*16,         d + 49152 + t*16);
    gload16(pBl + ko + (t+512)*16,   d + 49152 + (t+512)*16);
  };

  auto COMPUTE = [&](int b){
    const char* S = smem + b * 65536;
    #pragma unroll
    for (int ks = 0; ks < 2; ++ks){
      const int kc = ks*2 + lh;
      bf16x8 ah[4], al[4];
      #pragma unroll
      for (int m = 0; m < 4; ++m){
        const int ro = (kc*256 + wr*128 + m*32 + lr) * 16;
        ah[m] = *(const bf16x8*)(S + ro);
        al[m] = *(const bf16x8*)(S + 16384 + ro);
      }
      #pragma unroll
      for (int n = 0; n < 2; ++n){
        const int co = (kc*256 + wc*64 + n*32 + lr) * 16;
        bf16x8 bh = *(const bf16x8*)(S + 32768 + co);
        bf16x8 bl = *(const bf16x8*)(S + 49152 + co);
        #pragma unroll
        for (int m = 0; m < 4; ++m){
          acc[m][n] = __builtin_amdgcn_mfma_f32_32x32x16_bf16(ah[m], bh, acc[m][n], 0,0,0);
          acc[m][n] = __builtin_amdgcn_mfma_f32_32x32x16_bf16(ah[m], bl, acc[m][n], 0,0,0);
          acc[m][n] = __builtin_amdgcn_mfma_f32_32x32x16_bf16(al[m], bh, acc[m][n], 0,0,0);
        }
      }
    }
  };

  STAGE(0, 0);
  __syncthreads();                 // prologue drain
  int cur = 0;
  for (int k0 = 0; k0 < DIM; k0 += 32){
    if (k0 + 32 < DIM) STAGE(cur ^ 1, k0 + 32);  // issue next tile EARLY
    COMPUTE(cur);                                 // loads fly under MFMAs
    __syncthreads();                              // drains vmcnt post-compute
    cur ^= 1;
  }

  // epilogue: C/D map col=lane&31, row=(reg&3)+8*(reg>>2)+4*(lane>>5) [r10-verified]
  float c2v[2], clv[2]; int gc[2];
  #pragma unroll
  for (int n = 0; n < 2; ++n){
    gc[n]  = blockIdx.y*256 + wc*64 + n*32 + lr;
    c2v[n] = cn2[gc[n]]; clv[n] = cl[gc[n]];
  }
  float* rv = (float*)smem;             // [4 wc][256 rows]
  int*   ri = (int*)(smem + 4096);
  #pragma unroll
  for (int m = 0; m < 4; ++m){
    #pragma unroll
    for (int reg = 0; reg < 16; ++reg){
      const int rowL = wr*128 + m*32 + (reg & 3) + 8*(reg >> 2) + 4*lh;
      const float ir = i2r[blockIdx.x*256 + rowL];
      float bestv = INFINITY; int besti = 0x7fffffff;
      #pragma unroll
      for (int n = 0; n < 2; ++n){      // ascending col; padded cols: cn2=INF
        const float v = fmaf(c2v[n], ir, -(acc[m][n][reg] + clv[n]));
        if (v < bestv){ bestv = v; besti = gc[n]; }
      }
      #pragma unroll
      for (int mm = 1; mm < 32; mm <<= 1){   // 32-lane reduce (same rows)
        const float ov = __shfl_xor(bestv, mm, 64);
        const int   oi = __shfl_xor(besti, mm, 64);
        if (ov < bestv || (ov == bestv && oi < besti)){ bestv = ov; besti = oi; }
      }
      if (lr == 0){ rv[wc*256 + rowL] = bestv; ri[wc*256 + rowL] = besti; }
    }
  }
  __syncthreads();
  if (t < 256){                        // cross-wave (wc) reduce, rows=t
    float bestv = INFINITY; int besti = 0x7fffffff;
    #pragma unroll
    for (int s = 0; s < 4; ++s){
      const float v = rv[s*256 + t]; const int ix = ri[s*256 + t];
      if (v < bestv || (v == bestv && ix < besti)){ bestv = v; besti = ix; }
    }
    const int rowG = blockIdx.x*256 + t;
    pval[rowG*4 + blockIdx.y] = bestv;
    pidx[rowG*4 + blockIdx.y] = besti;
  }
}

// ---------------- final argmin over NT tile partials -----------------------
template<int NT>
__global__ __launch_bounds__(256) void argmin_final(const float* __restrict__ pval,
    const int* __restrict__ pidx, const int* __restrict__ labels,
    int* __restrict__ out){
  const int i = blockIdx.x * 256 + threadIdx.x;
  float bestv = INFINITY; int besti = 0x7fffffff;
  #pragma unroll
  for (int s = 0; s < NT; ++s){
    float v = pval[i*NT + s]; int ix = pidx[i*NT + s];
    if (v < bestv || (v == bestv && ix < besti)){ bestv = v; besti = ix; }
  }
  out[i] = labels[besti];
}

// ==================== fp32 fallback path (verified round 8) ================
__global__ __launch_bounds__(256) void rnorm_kernel(const float* __restrict__ feats,
                                                    float* __restrict__ rnorm) {
    const int row = blockIdx.x;
    const int t = threadIdx.x;
    const float4* p4 = (const float4*)(feats + (size_t)row * DIM);
    float4 v0 = p4[t];
    float4 v1 = p4[t + 256];
    float s = v0.x*v0.x + v0.y*v0.y + v0.z*v0.z + v0.w*v0.w
            + v1.x*v1.x + v1.y*v1.y + v1.z*v1.z + v1.w*v1.w;
    #pragma unroll
    for (int m = 1; m < 64; m <<= 1) s += __shfl_xor(s, m, 64);
    __shared__ float ws[4];
    if ((t & 63) == 0) ws[t >> 6] = s;
    __syncthreads();
    if (t == 0) {
        float tot = ws[0] + ws[1] + ws[2] + ws[3] + 1.0f;
        rnorm[row] = 1.0f / sqrtf(tot);
    }
}

__global__ __launch_bounds__(256) void cn2_kernel(const float* __restrict__ initc,
                                                  float* __restrict__ cn2) {
    const int j = blockIdx.x;
    const int t = threadIdx.x;
    const float* p = initc + (size_t)j * CDIM;
    float s = 0.f;
    for (int i = t; i < CDIM; i += 256) { float v = p[i]; s = fmaf(v, v, s); }
    #pragma unroll
    for (int m = 1; m < 64; m <<= 1) s += __shfl_xor(s, m, 64);
    __shared__ float ws[4];
    if ((t & 63) == 0) ws[t >> 6] = s;
    __syncthreads();
    if (t == 0) cn2[j] = ws[0] + ws[1] + ws[2] + ws[3];
}

__global__ __launch_bounds__(256) void dist_kernel(const float* __restrict__ feats,
                                                   const float* __restrict__ initc,
                                                   const float* __restrict__ rnorm,
                                                   const float* __restrict__ cn2,
                                                   float* __restrict__ pval,
                                                   int* __restrict__ pidx) {
    __shared__ __align__(16) float As[16][128 + 4];
    __shared__ __align__(16) float Bs[16][128 + 4];
    const int bm = blockIdx.x;
    const int bn = blockIdx.y;
    const int t  = threadIdx.x;
    const int tx = t & 15;
    const int ty = t >> 4;
    const int rowBase  = bm * 128;
    const int centBase = bn * 128;
    float acc[8][8];
    #pragma unroll
    for (int i = 0; i < 8; ++i)
        #pragma unroll
        for (int j = 0; j < 8; ++j) acc[i][j] = 0.f;
    const int ar  = t >> 2;
    const int ac4 = (t & 3) << 2;
    const int bc  = t >> 4;
    const int bcol = t & 15;
    auto cidx = [&](int j) { return (j < 4) ? (tx * 4 + j) : (64 + tx * 4 + (j - 4)); };
    for (int k0 = 0; k0 < DIM; k0 += 16) {
        #pragma unroll
        for (int p = 0; p < 2; ++p) {
            int row = p * 64 + ar;
            const float4 v = *(const float4*)(feats + (size_t)(rowBase + row) * DIM + k0 + ac4);
            As[ac4 + 0][row] = v.x;
            As[ac4 + 1][row] = v.y;
            As[ac4 + 2][row] = v.z;
            As[ac4 + 3][row] = v.w;
        }
        #pragma unroll
        for (int p = 0; p < 8; ++p) {
            int cent = p * 16 + bc;
            int gj = centBase + cent;
            Bs[bcol][cent] = (gj < K_CENT) ? initc[(size_t)gj * CDIM + k0 + bcol] : 0.f;
        }
        __syncthreads();
        #pragma unroll
        for (int kk = 0; kk < 16; ++kk) {
            float a[8], b[8];
            *(float4*)&a[0] = *(const float4*)&As[kk][ty * 8];
            *(float4*)&a[4] = *(const float4*)&As[kk][ty * 8 + 4];
            *(float4*)&b[0] = *(const float4*)&Bs[kk][tx * 4];
            *(float4*)&b[4] = *(const float4*)&Bs[kk][64 + tx * 4];
            #pragma unroll
            for (int i = 0; i < 8; ++i)
                #pragma unroll
                for (int j = 0; j < 8; ++j)
                    acc[i][j] = fmaf(a[i], b[j], acc[i][j]);
        }
        __syncthreads();
    }
    float rn[8];
    #pragma unroll
    for (int i = 0; i < 8; ++i) rn[i] = rnorm[rowBase + ty * 8 + i];
    float cle[8], c2[8];
    #pragma unroll
    for (int j = 0; j < 8; ++j) {
        int gj = centBase + cidx(j);
        cle[j] = (gj < K_CENT) ? initc[(size_t)gj * CDIM + DIM] : 0.f;
        c2[j] = (gj < K_CENT) ? cn2[gj] : INFINITY;
    }
    #pragma unroll
    for (int i = 0; i < 8; ++i) {
        float bestv = INFINITY;
        int   besti = 0x7fffffff;
        #pragma unroll
        for (int j = 0; j < 8; ++j) {
            int gj = centBase + cidx(j);
            float v = (gj < K_CENT) ? (c2[j] - 2.0f * rn[i] * (acc[i][j] + cle[j])) : INFINITY;
            if (v < bestv) { bestv = v; besti = gj; }
        }
        #pragma unroll
        for (int m = 1; m < 16; m <<= 1) {
            float ov = __shfl_xor(bestv, m, 64);
            int   oi = __shfl_xor(besti, m, 64);
            if (ov < bestv || (ov == bestv && oi < besti)) { bestv = ov; besti = oi; }
        }
        if (tx == 0) {
            int row = rowBase + ty * 8 + i;
            pval[row * 8 + bn] = bestv;
            pidx[row * 8 + bn] = besti;
        }
    }
}

// ==================== launch ==============================================
extern "C" void kernel_launch(void* const* d_in, const int* in_sizes, int n_in,
                              void* d_out, int out_size, void* d_ws, size_t ws_size,
                              hipStream_t stream) {
    const float* feats  = (const float*)d_in[0];   // [16384, 2048] fp32
    const float* initc  = (const float*)d_in[1];   // [1000, 2049] fp32
    const int*   labels = (const int*)d_in[2];     // [1000] int32 (arange)
    int* out = (int*)d_out;                        // [16384] int32
    char* ws = (char*)d_ws;

    if (ws_size >= WS_NEED) {
        unsigned short* AhT = (unsigned short*)(ws + WS_AH);
        unsigned short* AlT = (unsigned short*)(ws + WS_AL);
        unsigned short* BhT = (unsigned short*)(ws + WS_BH);
        unsigned short* BlT = (unsigned short*)(ws + WS_BL);
        float* psA = (float*)(ws + WS_PSA);
        float* psB = (float*)(ws + WS_PSB);
        float* ir  = (float*)(ws + WS_IR);
        float* c2  = (float*)(ws + WS_CN2);
        float* clp = (float*)(ws + WS_CL);
        float* pv  = (float*)(ws + WS_PV);
        int*   pi  = (int*)  (ws + WS_PI);

        prep_split<<<dim3(64, 4), 256, 0, stream>>>(feats, DIM, N_ROWS, AhT, AlT, psA, N_ROWS);
        prep_split<<<dim3(4, 4),  256, 0, stream>>>(initc, CDIM, K_CENT, BhT, BlT, psB, KPAD);
        finalize_rows<<<64, 256, 0, stream>>>(psA, ir);
        finalize_cents<<<4, 256, 0, stream>>>(psB, initc, c2, clp);
        dist_mfma2<<<dim3(64, 4), 512, 0, stream>>>(AhT, AlT, BhT, BlT, ir, c2, clp, pv, pi);
        argmin_final<4><<<N_ROWS / 256, 256, 0, stream>>>(pv, pi, labels, out);
    } else {
        // -------- fp32 fallback (verified) --------
        float* rnorm = (float*)(ws);
        float* cn2   = (float*)(ws + 65536);
        float* pval  = (float*)(ws + 73728);
        int*   pidx  = (int*)  (ws + 73728 + 524288);

        rnorm_kernel<<<N_ROWS, 256, 0, stream>>>(feats, rnorm);
        cn2_kernel<<<K_CENT, 256, 0, stream>>>(initc, cn2);
        dim3 grid(N_ROWS / 128, 8);
        dist_kernel<<<grid, 256, 0, stream>>>(feats, initc, rnorm, cn2, pval, pidx);
        argmin_final<8><<<N_ROWS / 256, 256, 0, stream>>>(pval, pidx, labels, out);
    }
}